// Round 6
// baseline (404.320 us; speedup 1.0000x reference)
//
#include <hip/hip_runtime.h>

#define GRID 32
#define NT 48
#define BLK 256
#define PPB 64            // points per block (one per lane)
#define RPW 12            // t-rows per wave (4 waves * 12 = 48)

// Per-edge packed info: bits [0]=base_x, [1]=base_y, [2]=base_z, [4:3]=axis.
#define EDGE_PACK ( (0ULL<<0) | (9ULL<<5) | (2ULL<<10) | (8ULL<<15) | \
                    (4ULL<<20) | (13ULL<<25) | (6ULL<<30) | (12ULL<<35) | \
                    (16ULL<<40) | (17ULL<<45) | (19ULL<<50) | (18ULL<<55) )

// Ericson closest-point on p-relative vectors (A=p-a, B=p-b, C=p-c).
// All regions unified as q = a + ab*v + ac*w; cascade (reference `where`
// order, later wins) picks (nv, nw, den), ONE rcp serves every region.
// d1..d6/va/vb/vc/d43/d56 are computed contract-OFF in numpy's evaluation
// order so region selection cannot flip with codegen (r5 lesson: contracted
// condition inputs pushed absmax to 0.106 vs threshold 0.12).
__device__ __forceinline__ float tri_dist_sq(float4 A, float4 B, float4 C) {
    float abx = A.x - B.x, aby = A.y - B.y, abz = A.z - B.z;
    float acx = A.x - C.x, acy = A.y - C.y, acz = A.z - C.z;
    float d1, d2, d3, d4, d5, d6, va, vb, vc, d43, d56;
    {
#pragma clang fp contract(off)
        d1 = (abx * A.x + aby * A.y) + abz * A.z;
        d2 = (acx * A.x + acy * A.y) + acz * A.z;
        d3 = (abx * B.x + aby * B.y) + abz * B.z;
        d4 = (acx * B.x + acy * B.y) + acz * B.z;
        d5 = (abx * C.x + aby * C.y) + abz * C.z;
        d6 = (acx * C.x + acy * C.y) + acz * C.z;
        vc = d1 * d4 - d3 * d2;
        vb = d5 * d2 - d1 * d6;
        va = d3 * d6 - d5 * d4;
        d43 = d4 - d3;
        d56 = d5 - d6;
    }
    bool c_bc = (va <= 0.0f) & (d43 >= 0.0f) & (d56 >= 0.0f);
    bool c_ac = (vb <= 0.0f) & (d2 >= 0.0f) & (d6 <= 0.0f);
    bool c_c  = (d6 >= 0.0f) & (d5 <= d6);
    bool c_ab = (vc <= 0.0f) & (d1 >= 0.0f) & (d3 <= 0.0f);
    bool c_b  = (d3 >= 0.0f) & (d4 <= d3);
    bool c_a  = (d1 <= 0.0f) & (d2 <= 0.0f);

    float den = va + vb + vc;
    den = c_bc ? (d43 + d56) : den;
    den = c_ac ? (d2 - d6)   : den;
    den = c_c  ? 1.0f        : den;
    den = c_ab ? (d1 - d3)   : den;
    den = (c_b | c_a) ? 1.0f : den;
    den = (fabsf(den) > 1e-12f) ? den : 1e-12f;
    float r = __builtin_amdgcn_rcpf(den);

    float nw = vc;
    nw = c_bc ? d43  : nw;
    nw = c_ac ? d2   : nw;
    nw = c_c  ? 1.0f : nw;
    nw = (c_ab | c_b | c_a) ? 0.0f : nw;

    // bc uses final clamped den: den-d43 == d56 in the sane regime, and
    // == eps (-> v=1, q=b) in the fully-degenerate clamp regime, matching ref.
    float nv = vb;
    nv = c_bc ? (den - d43) : nv;
    nv = (c_ac | c_c) ? 0.0f : nv;
    nv = c_ab ? d1   : nv;
    nv = c_b  ? 1.0f : nv;
    nv = c_a  ? 0.0f : nv;

    float v = nv * r;
    float w = nw * r;
    float dx = A.x - abx * v - acx * w;
    float dy = A.y - aby * v - acy * w;
    float dz = A.z - abz * v - acz * w;
    return dx * dx + dy * dy + dz * dz;
}

__global__ __launch_bounds__(BLK) void ptd_kernel(
    const float* __restrict__ offset,     // (3,33,33,33)
    const float* __restrict__ points,     // (N,3)
    const int*   __restrict__ tri_table,  // (48,3,3)
    float*       __restrict__ out,        // (32768,48)
    int n)
{
    // Per-point rows of p-relative edge vertices (row = lane), stride 13
    // float4s. 64*13*16 = 13312 B -> 8 blocks/CU fits in 106 KB LDS.
    __shared__ float4 v_s[PPB * 13];
    __shared__ int t_tab[NT * 3];         // packed i0 | i1<<8 | i2<<16

    const int tid  = threadIdx.x;
    const int lane = tid & 63;
    const int wv   = tid >> 6;            // wave id 0..3
    const int pt   = blockIdx.x * PPB + lane;
    const bool active = (pt < n);

    if (tid < NT * 3) {
        int i0 = tri_table[tid * 3 + 0];
        int i1 = tri_table[tid * 3 + 1];
        int i2 = tri_table[tid * 3 + 2];
        t_tab[tid] = i0 | (i1 << 8) | (i2 << 16);
    }

    int cx = 0, cy = 0, cz = 0;
    if (active) {
        float px = points[pt * 3 + 0];
        float py = points[pt * 3 + 1];
        float pz = points[pt * 3 + 2];
        cx = min(max((int)floorf(px), 0), GRID - 1);
        cy = min(max((int)floorf(py), 0), GRID - 1);
        cz = min(max((int)floorf(pz), 0), GRID - 1);
        float lx = px - (float)cx;
        float ly = py - (float)cy;
        float lz = pz - (float)cz;
        // Each of the 4 waves fills 3 of the 12 edges for ITS lane's row.
#pragma unroll
        for (int j = 0; j < 3; j++) {
            int e = wv * 3 + j;
            unsigned nib = (unsigned)(EDGE_PACK >> (5 * e)) & 31u;
            int gx = cx + (int)(nib & 1u);
            int gy = cy + (int)((nib >> 1) & 1u);
            int gz = cz + (int)((nib >> 2) & 1u);
            int ax = (int)(nib >> 3);
            float t = offset[((ax * 33 + gx) * 33 + gy) * 33 + gz];
            float vx = (ax == 0) ? t : (float)(nib & 1u);
            float vy = (ax == 1) ? t : (float)((nib >> 1) & 1u);
            float vz = (ax == 2) ? t : (float)((nib >> 2) & 1u);
            v_s[lane * 13 + e] = make_float4(lx - vx, ly - vy, lz - vz, 0.0f);
        }
    }
    __syncthreads();

    if (!active) return;

    const float4* vrow = &v_s[lane * 13];
    float* outp = out + ((((cx * GRID) + cy) * GRID + cz) * NT);

    for (int rr = 0; rr < RPW; rr++) {
        const int row = wv * RPW + rr;    // wave-uniform
        // Indices are identical across the wave: force SGPR so unpack and
        // address math ride the scalar pipe.
        int p0 = __builtin_amdgcn_readfirstlane(t_tab[row * 3 + 0]);
        int p1 = __builtin_amdgcn_readfirstlane(t_tab[row * 3 + 1]);
        int p2 = __builtin_amdgcn_readfirstlane(t_tab[row * 3 + 2]);
        // Software pipeline: keep the next tri's loads in flight while the
        // current one computes (raises live VGPRs deliberately; r5's
        // 24-VGPR serial schedule exposed LDS latency+conflicts).
        float4 A0 = vrow[p0 & 255], B0 = vrow[(p0 >> 8) & 255], C0 = vrow[(p0 >> 16) & 255];
        float4 A1 = vrow[p1 & 255], B1 = vrow[(p1 >> 8) & 255], C1 = vrow[(p1 >> 16) & 255];
        float d0 = tri_dist_sq(A0, B0, C0);
        float4 A2 = vrow[p2 & 255], B2 = vrow[(p2 >> 8) & 255], C2 = vrow[(p2 >> 16) & 255];
        float d1 = tri_dist_sq(A1, B1, C1);
        float dmin = fminf(d0, d1);
        float d2 = tri_dist_sq(A2, B2, C2);
        dmin = fminf(dmin, d2);
        atomicAdd(&outp[row], dmin);
    }
}

extern "C" void kernel_launch(void* const* d_in, const int* in_sizes, int n_in,
                              void* d_out, int out_size, void* d_ws, size_t ws_size,
                              hipStream_t stream) {
    const float* offset    = (const float*)d_in[0];
    const float* points    = (const float*)d_in[1];
    const int*   tri_table = (const int*)d_in[2];
    float* out = (float*)d_out;
    int n = in_sizes[1] / 3;  // 131072 points

    // Output is accumulated via atomics; harness poisons d_out with 0xAA.
    hipMemsetAsync(d_out, 0, (size_t)out_size * sizeof(float), stream);

    int blocks = (n + PPB - 1) / PPB;     // 2048
    ptd_kernel<<<blocks, BLK, 0, stream>>>(offset, points, tri_table, out, n);
}

// Round 7
// 163.414 us; speedup vs baseline: 2.4742x; 2.4742x over previous
//
#include <hip/hip_runtime.h>

#define GRID 32
#define NCELL (GRID * GRID * GRID)   // 32768
#define NT 48
#define BLK 256
#define SPLIT 16                 // threads per point; each handles 3 t-rows
#define PPB (BLK / SPLIT)        // 16 points per block

// Per-edge packed info: bits [0]=base_x, [1]=base_y, [2]=base_z, [4:3]=axis.
#define EDGE_PACK ( (0ULL<<0) | (9ULL<<5) | (2ULL<<10) | (8ULL<<15) | \
                    (4ULL<<20) | (13ULL<<25) | (6ULL<<30) | (12ULL<<35) | \
                    (16ULL<<40) | (17ULL<<45) | (19ULL<<50) | (18ULL<<55) )

__device__ __forceinline__ int cell_of(float p) {
    return min(max((int)floorf(p), 0), GRID - 1);
}

// Ericson closest-point on p-relative vectors (A=p-a, B=p-b, C=p-c).
// Regions unified as q = a + ab*v + ac*w; cascade (reference `where` order,
// later wins) picks (nv, nw, den); ONE rcp serves every region. Condition
// inputs d1..d6/va/vb/vc computed contract-OFF in numpy's evaluation order
// (r5 lesson: contracted condition inputs pushed absmax to 0.106).
// Degenerate-bc: nv_bc = den_clamped - d43 -> v=1 (q=b) when b==c, as ref.
__device__ __forceinline__ float tri_dist_sq(float4 A, float4 B, float4 C) {
    float abx = A.x - B.x, aby = A.y - B.y, abz = A.z - B.z;
    float acx = A.x - C.x, acy = A.y - C.y, acz = A.z - C.z;
    float d1, d2, d3, d4, d5, d6, va, vb, vc, d43, d56;
    {
#pragma clang fp contract(off)
        d1 = (abx * A.x + aby * A.y) + abz * A.z;
        d2 = (acx * A.x + acy * A.y) + acz * A.z;
        d3 = (abx * B.x + aby * B.y) + abz * B.z;
        d4 = (acx * B.x + acy * B.y) + acz * B.z;
        d5 = (abx * C.x + aby * C.y) + abz * C.z;
        d6 = (acx * C.x + acy * C.y) + acz * C.z;
        vc = d1 * d4 - d3 * d2;
        vb = d5 * d2 - d1 * d6;
        va = d3 * d6 - d5 * d4;
        d43 = d4 - d3;
        d56 = d5 - d6;
    }
    bool c_bc = (va <= 0.0f) & (d43 >= 0.0f) & (d56 >= 0.0f);
    bool c_ac = (vb <= 0.0f) & (d2 >= 0.0f) & (d6 <= 0.0f);
    bool c_c  = (d6 >= 0.0f) & (d5 <= d6);
    bool c_ab = (vc <= 0.0f) & (d1 >= 0.0f) & (d3 <= 0.0f);
    bool c_b  = (d3 >= 0.0f) & (d4 <= d3);
    bool c_a  = (d1 <= 0.0f) & (d2 <= 0.0f);

    float den = va + vb + vc;
    den = c_bc ? (d43 + d56) : den;
    den = c_ac ? (d2 - d6)   : den;
    den = c_c  ? 1.0f        : den;
    den = c_ab ? (d1 - d3)   : den;
    den = (c_b | c_a) ? 1.0f : den;
    den = (fabsf(den) > 1e-12f) ? den : 1e-12f;
    float r = __builtin_amdgcn_rcpf(den);

    float nw = vc;
    nw = c_bc ? d43  : nw;
    nw = c_ac ? d2   : nw;
    nw = c_c  ? 1.0f : nw;
    nw = (c_ab | c_b | c_a) ? 0.0f : nw;

    float nv = vb;
    nv = c_bc ? (den - d43) : nv;
    nv = (c_ac | c_c) ? 0.0f : nv;
    nv = c_ab ? d1   : nv;
    nv = c_b  ? 1.0f : nv;
    nv = c_a  ? 0.0f : nv;

    float v = nv * r;
    float w = nw * r;
    float dx = A.x - abx * v - acx * w;
    float dy = A.y - aby * v - acy * w;
    float dz = A.z - abz * v - acz * w;
    return dx * dx + dy * dy + dz * dz;
}

// ---------- sort-by-cell pipeline ----------

__global__ void hist_kernel(const float* __restrict__ pts, int* __restrict__ cnt, int n) {
    int i = blockIdx.x * blockDim.x + threadIdx.x;
    if (i >= n) return;
    int cx = cell_of(pts[3 * i + 0]);
    int cy = cell_of(pts[3 * i + 1]);
    int cz = cell_of(pts[3 * i + 2]);
    atomicAdd(&cnt[(cx * GRID + cy) * GRID + cz], 1);
}

// Single workgroup: exclusive scan of 32768 counts. 1024 threads x 32 each.
__global__ __launch_bounds__(1024) void scan_kernel(
    const int* __restrict__ cnt, int* __restrict__ start, int* __restrict__ cursor) {
    __shared__ int part[1024];
    const int tid = threadIdx.x;
    const int base = tid * 32;
    int s = 0;
    for (int j = 0; j < 32; j++) s += cnt[base + j];
    part[tid] = s;
    __syncthreads();
    // Hillis-Steele inclusive scan over the 1024 partials.
    for (int off = 1; off < 1024; off <<= 1) {
        int add = (tid >= off) ? part[tid - off] : 0;
        __syncthreads();
        part[tid] += add;
        __syncthreads();
    }
    int run = (tid == 0) ? 0 : part[tid - 1];
    for (int j = 0; j < 32; j++) {
        int c = cnt[base + j];
        start[base + j]  = run;
        cursor[base + j] = run;
        run += c;
    }
    if (tid == 1023) start[NCELL] = run;
}

__global__ void scatter_kernel(const float* __restrict__ pts, int* __restrict__ cursor,
                               int* __restrict__ sorted, int n) {
    int i = blockIdx.x * blockDim.x + threadIdx.x;
    if (i >= n) return;
    int cx = cell_of(pts[3 * i + 0]);
    int cy = cell_of(pts[3 * i + 1]);
    int cz = cell_of(pts[3 * i + 2]);
    int pos = atomicAdd(&cursor[(cx * GRID + cy) * GRID + cz], 1);
    sorted[pos] = i;
}

// Main compute: r4 structure, but results go to coalesced scratch
// (scratch[sp*48 + t], sp = sorted slot) with PLAIN stores — no atomics.
// r3-r6 evidence: scattered atomic write-back pinned wall at WRITE/~1TB/s.
__global__ __launch_bounds__(BLK) void compute_kernel(
    const float* __restrict__ offset,     // (3,33,33,33)
    const float* __restrict__ points,     // (N,3)
    const int*   __restrict__ tri_table,  // (48,3,3)
    const int*   __restrict__ sorted,     // (N) point idx by sorted slot
    float*       __restrict__ scratch,    // (N,48) by sorted slot
    int n)
{
    __shared__ float4 v_s[PPB * 13];      // p-relative edge verts, stride 13
    __shared__ int t_tab[NT * 3];         // packed i0 | i1<<8 | i2<<16

    const int tid = threadIdx.x;
    const int g   = blockIdx.x * BLK + tid;
    const int sp  = g >> 4;               // sorted slot
    const int grp = tid & 15;
    const int pl  = tid >> 4;
    const bool active = (sp < n);

    if (tid < NT * 3) {
        int i0 = tri_table[tid * 3 + 0];
        int i1 = tri_table[tid * 3 + 1];
        int i2 = tri_table[tid * 3 + 2];
        t_tab[tid] = i0 | (i1 << 8) | (i2 << 16);
    }

    if (active) {
        int pt = sorted[sp];
        float px = points[pt * 3 + 0];
        float py = points[pt * 3 + 1];
        float pz = points[pt * 3 + 2];
        int cx = cell_of(px), cy = cell_of(py), cz = cell_of(pz);
        if (grp < 12) {
            float lx = px - (float)cx;
            float ly = py - (float)cy;
            float lz = pz - (float)cz;
            unsigned nib = (unsigned)(EDGE_PACK >> (5 * grp)) & 31u;
            int gx = cx + (int)(nib & 1u);
            int gy = cy + (int)((nib >> 1) & 1u);
            int gz = cz + (int)((nib >> 2) & 1u);
            int ax = (int)(nib >> 3);
            float t = offset[((ax * 33 + gx) * 33 + gy) * 33 + gz];
            float vx = (ax == 0) ? t : (float)(nib & 1u);
            float vy = (ax == 1) ? t : (float)((nib >> 1) & 1u);
            float vz = (ax == 2) ? t : (float)((nib >> 2) & 1u);
            v_s[pl * 13 + grp] = make_float4(lx - vx, ly - vy, lz - vz, 0.0f);
        }
    }
    __syncthreads();

    if (!active) return;

    const float4* vrow = &v_s[pl * 13];
    float* outp = scratch + (size_t)sp * NT;

#pragma unroll
    for (int r = 0; r < 3; r++) {
        const int t = grp * 3 + r;
        float dmin;
#pragma unroll
        for (int k = 0; k < 3; k++) {
            int packed = t_tab[t * 3 + k];
            float4 A = vrow[packed & 255];
            float4 B = vrow[(packed >> 8) & 255];
            float4 C = vrow[(packed >> 16) & 255];
            float d = tri_dist_sq(A, B, C);
            dmin = (k == 0) ? d : fminf(dmin, d);
        }
        outp[t] = dmin;                   // plain coalesced store
    }
}

// Segmented reduce: thread = (cell, t); sums contiguous scratch rows of its
// cell; ONE plain write per output element (6 MB written once).
__global__ void reduce_kernel(const int* __restrict__ start,
                              const float* __restrict__ scratch,
                              float* __restrict__ out) {
    int g = blockIdx.x * blockDim.x + threadIdx.x;
    if (g >= NCELL * NT) return;
    int cell = g / NT;
    int t    = g - cell * NT;
    int s0 = start[cell], s1 = start[cell + 1];
    float acc = 0.0f;
    for (int i = s0; i < s1; i++) acc += scratch[(size_t)i * NT + t];
    out[g] = acc;
}

// ---------- fallback (ws too small): r4-style atomic path ----------

__global__ __launch_bounds__(BLK) void atomic_kernel(
    const float* __restrict__ offset, const float* __restrict__ points,
    const int* __restrict__ tri_table, float* __restrict__ out, int n)
{
    __shared__ float4 v_s[PPB * 13];
    __shared__ int t_tab[NT * 3];
    const int tid = threadIdx.x;
    const int g   = blockIdx.x * BLK + tid;
    const int pt  = g >> 4;
    const int grp = tid & 15;
    const int pl  = tid >> 4;
    const bool active = (pt < n);
    if (tid < NT * 3) {
        int i0 = tri_table[tid * 3 + 0];
        int i1 = tri_table[tid * 3 + 1];
        int i2 = tri_table[tid * 3 + 2];
        t_tab[tid] = i0 | (i1 << 8) | (i2 << 16);
    }
    int cx = 0, cy = 0, cz = 0;
    if (active) {
        float px = points[pt * 3 + 0];
        float py = points[pt * 3 + 1];
        float pz = points[pt * 3 + 2];
        cx = cell_of(px); cy = cell_of(py); cz = cell_of(pz);
        if (grp < 12) {
            float lx = px - (float)cx, ly = py - (float)cy, lz = pz - (float)cz;
            unsigned nib = (unsigned)(EDGE_PACK >> (5 * grp)) & 31u;
            int gx = cx + (int)(nib & 1u);
            int gy = cy + (int)((nib >> 1) & 1u);
            int gz = cz + (int)((nib >> 2) & 1u);
            int ax = (int)(nib >> 3);
            float t = offset[((ax * 33 + gx) * 33 + gy) * 33 + gz];
            float vx = (ax == 0) ? t : (float)(nib & 1u);
            float vy = (ax == 1) ? t : (float)((nib >> 1) & 1u);
            float vz = (ax == 2) ? t : (float)((nib >> 2) & 1u);
            v_s[pl * 13 + grp] = make_float4(lx - vx, ly - vy, lz - vz, 0.0f);
        }
    }
    __syncthreads();
    if (!active) return;
    const float4* vrow = &v_s[pl * 13];
    float* outp = out + ((((cx * GRID) + cy) * GRID + cz) * NT);
#pragma unroll
    for (int r = 0; r < 3; r++) {
        const int t = grp * 3 + r;
        float dmin;
#pragma unroll
        for (int k = 0; k < 3; k++) {
            int packed = t_tab[t * 3 + k];
            float4 A = vrow[packed & 255];
            float4 B = vrow[(packed >> 8) & 255];
            float4 C = vrow[(packed >> 16) & 255];
            float d = tri_dist_sq(A, B, C);
            dmin = (k == 0) ? d : fminf(dmin, d);
        }
        atomicAdd(&outp[t], dmin);
    }
}

extern "C" void kernel_launch(void* const* d_in, const int* in_sizes, int n_in,
                              void* d_out, int out_size, void* d_ws, size_t ws_size,
                              hipStream_t stream) {
    const float* offset    = (const float*)d_in[0];
    const float* points    = (const float*)d_in[1];
    const int*   tri_table = (const int*)d_in[2];
    float* out = (float*)d_out;
    int n = in_sizes[1] / 3;  // 131072 points

    // ws layout: cnt[NCELL] | cursor[NCELL] | start[NCELL+1] | sorted[n] | scratch[n*48]
    size_t need = ((size_t)NCELL * 2 + (NCELL + 1) + n + (size_t)n * NT) * 4;
    if (ws_size >= need) {
        int* cnt    = (int*)d_ws;
        int* cursor = cnt + NCELL;
        int* start  = cursor + NCELL;
        int* sorted = start + (NCELL + 1);
        float* scratch = (float*)(sorted + n);

        hipMemsetAsync(cnt, 0, NCELL * sizeof(int), stream);
        int pblk = (n + 255) / 256;
        hist_kernel<<<pblk, 256, 0, stream>>>(points, cnt, n);
        scan_kernel<<<1, 1024, 0, stream>>>(cnt, start, cursor);
        scatter_kernel<<<pblk, 256, 0, stream>>>(points, cursor, sorted, n);
        long total = (long)n * SPLIT;
        compute_kernel<<<(int)((total + BLK - 1) / BLK), BLK, 0, stream>>>(
            offset, points, tri_table, sorted, scratch, n);
        reduce_kernel<<<(NCELL * NT + 255) / 256, 256, 0, stream>>>(start, scratch, out);
    } else {
        hipMemsetAsync(d_out, 0, (size_t)out_size * sizeof(float), stream);
        long total = (long)n * SPLIT;
        atomic_kernel<<<(int)((total + BLK - 1) / BLK), BLK, 0, stream>>>(
            offset, points, tri_table, out, n);
    }
}

// Round 8
// 129.412 us; speedup vs baseline: 3.1243x; 1.2627x over previous
//
#include <hip/hip_runtime.h>

#define GRID 32
#define NT 48
#define BLK 256
#define SPLIT 16                 // threads per point; each handles 3 t-rows
#define PPB (BLK / SPLIT)        // 16 points per block

// Per-edge packed info: bits [0]=base_x, [1]=base_y, [2]=base_z, [4:3]=axis.
#define EDGE_PACK ( (0ULL<<0) | (9ULL<<5) | (2ULL<<10) | (8ULL<<15) | \
                    (4ULL<<20) | (13ULL<<25) | (6ULL<<30) | (12ULL<<35) | \
                    (16ULL<<40) | (17ULL<<45) | (19ULL<<50) | (18ULL<<55) )

__device__ __forceinline__ int cell_of(float p) {
    return min(max((int)floorf(p), 0), GRID - 1);
}

// Ericson closest-point on p-relative vectors (A=p-a, B=p-b, C=p-c).
// Regions unified as q = a + ab*v + ac*w; cascade (reference `where` order,
// later wins) picks (nv, nw, den); ONE rcp serves every region. Condition
// inputs d1..d6/va/vb/vc computed contract-OFF in numpy's evaluation order
// (r5: contracted condition inputs pushed absmax to 0.106 vs threshold 0.12;
// this exact form measures 0.0039 in r6/r7).
// nv merge (r8): (c_ac|c_c|c_a)->0 in one select. Override conflicts with
// later c_ab/c_b only occur when d1=d3=0 => |ab|^2=0 => a==b bitwise, where
// both branches yield identical q — safe.
__device__ __forceinline__ float tri_dist_sq(float4 A, float4 B, float4 C) {
    float abx = A.x - B.x, aby = A.y - B.y, abz = A.z - B.z;
    float acx = A.x - C.x, acy = A.y - C.y, acz = A.z - C.z;
    float d1, d2, d3, d4, d5, d6, va, vb, vc, d43, d56;
    {
#pragma clang fp contract(off)
        d1 = (abx * A.x + aby * A.y) + abz * A.z;
        d2 = (acx * A.x + acy * A.y) + acz * A.z;
        d3 = (abx * B.x + aby * B.y) + abz * B.z;
        d4 = (acx * B.x + acy * B.y) + acz * B.z;
        d5 = (abx * C.x + aby * C.y) + abz * C.z;
        d6 = (acx * C.x + acy * C.y) + acz * C.z;
        vc = d1 * d4 - d3 * d2;
        vb = d5 * d2 - d1 * d6;
        va = d3 * d6 - d5 * d4;
        d43 = d4 - d3;
        d56 = d5 - d6;
    }
    bool c_bc = (va <= 0.0f) & (d43 >= 0.0f) & (d56 >= 0.0f);
    bool c_ac = (vb <= 0.0f) & (d2 >= 0.0f) & (d6 <= 0.0f);
    bool c_c  = (d6 >= 0.0f) & (d5 <= d6);
    bool c_ab = (vc <= 0.0f) & (d1 >= 0.0f) & (d3 <= 0.0f);
    bool c_b  = (d3 >= 0.0f) & (d4 <= d3);
    bool c_a  = (d1 <= 0.0f) & (d2 <= 0.0f);

    float den = va + vb + vc;
    den = c_bc ? (d43 + d56) : den;
    den = c_ac ? (d2 - d6)   : den;
    den = c_c  ? 1.0f        : den;
    den = c_ab ? (d1 - d3)   : den;
    den = (c_b | c_a) ? 1.0f : den;
    den = (fabsf(den) > 1e-12f) ? den : 1e-12f;
    float r = __builtin_amdgcn_rcpf(den);

    float nw = vc;
    nw = c_bc ? d43  : nw;
    nw = c_ac ? d2   : nw;
    nw = c_c  ? 1.0f : nw;
    nw = (c_ab | c_b | c_a) ? 0.0f : nw;

    float nv = vb;
    nv = c_bc ? (den - d43)        : nv;   // == d56 sane / eps-clamped -> v=1
    nv = (c_ac | c_c | c_a) ? 0.0f : nv;   // merged (see header comment)
    nv = c_ab ? d1   : nv;
    nv = c_b  ? 1.0f : nv;

    float v = nv * r;
    float w = nw * r;
    float dx = A.x - abx * v - acx * w;
    float dy = A.y - aby * v - acy * w;
    float dz = A.z - abz * v - acz * w;
    return dx * dx + dy * dy + dz * dz;
}

__global__ __launch_bounds__(BLK) void ptd_kernel(
    const float* __restrict__ offset,     // (3,33,33,33)
    const float* __restrict__ points,     // (N,3)
    const int*   __restrict__ tri_table,  // (48,3,3)
    float*       __restrict__ out,        // (32768,48)
    int n)
{
    // Per-point rows of p-relative edge vertices, stride 13 float4s.
    __shared__ float4 v_s[PPB * 13];
    // Packed tri indices, 12-int (48 B, 16 B-aligned) rows per grp:
    // row[grp][c] for c<9 = i0|i1<<8|i2<<16 of (t = grp*3 + c/3, k = c%3).
    __shared__ int t_tab4[16][12];

    const int tid = threadIdx.x;
    const int g   = blockIdx.x * BLK + tid;
    const int pt  = g >> 4;               // SPLIT=16
    const int grp = tid & 15;
    const int pl  = tid >> 4;
    const bool active = (pt < n);

    if (tid < 144) {                      // tid enumerates (t,k) = tid/3, tid%3
        int i0 = tri_table[tid * 3 + 0];
        int i1 = tri_table[tid * 3 + 1];
        int i2 = tri_table[tid * 3 + 2];
        t_tab4[tid / 9][tid % 9] = i0 | (i1 << 8) | (i2 << 16);
    }

    int cx = 0, cy = 0, cz = 0;
    if (active) {
        float px = points[pt * 3 + 0];
        float py = points[pt * 3 + 1];
        float pz = points[pt * 3 + 2];
        cx = cell_of(px); cy = cell_of(py); cz = cell_of(pz);
        if (grp < 12) {
            float lx = px - (float)cx, ly = py - (float)cy, lz = pz - (float)cz;
            unsigned nib = (unsigned)(EDGE_PACK >> (5 * grp)) & 31u;
            int gx = cx + (int)(nib & 1u);
            int gy = cy + (int)((nib >> 1) & 1u);
            int gz = cz + (int)((nib >> 2) & 1u);
            int ax = (int)(nib >> 3);
            float t = offset[((ax * 33 + gx) * 33 + gy) * 33 + gz];
            float vx = (ax == 0) ? t : (float)(nib & 1u);
            float vy = (ax == 1) ? t : (float)((nib >> 1) & 1u);
            float vz = (ax == 2) ? t : (float)((nib >> 2) & 1u);
            v_s[pl * 13 + grp] = make_float4(lx - vx, ly - vy, lz - vz, 0.0f);
        }
    }
    __syncthreads();

    if (!active) return;

    // Fetch this thread's 9 packed tri entries with 2 wide LDS reads.
    const int* tp = &t_tab4[grp][0];
    int4 qa = *(const int4*)tp;
    int4 qb = *(const int4*)(tp + 4);
    int pk[9] = {qa.x, qa.y, qa.z, qa.w, qb.x, qb.y, qb.z, qb.w, tp[8]};

    const float4* vrow = &v_s[pl * 13];
    float* outp = out + ((((cx * GRID) + cy) * GRID + cz) * NT);

#pragma unroll
    for (int r = 0; r < 3; r++) {
        const int t = grp * 3 + r;
        float dmin;
#pragma unroll
        for (int k = 0; k < 3; k++) {
            int packed = pk[r * 3 + k];
            float4 A = vrow[packed & 255];
            float4 B = vrow[(packed >> 8) & 255];
            float4 C = vrow[(packed >> 16) & 255];
            float d = tri_dist_sq(A, B, C);
            dmin = (k == 0) ? d : fminf(dmin, d);
        }
        atomicAdd(&outp[t], dmin);
    }
}

extern "C" void kernel_launch(void* const* d_in, const int* in_sizes, int n_in,
                              void* d_out, int out_size, void* d_ws, size_t ws_size,
                              hipStream_t stream) {
    const float* offset    = (const float*)d_in[0];
    const float* points    = (const float*)d_in[1];
    const int*   tri_table = (const int*)d_in[2];
    float* out = (float*)d_out;
    int n = in_sizes[1] / 3;  // 131072 points

    // Output accumulated via atomics; harness poisons d_out with 0xAA.
    hipMemsetAsync(d_out, 0, (size_t)out_size * sizeof(float), stream);

    long total = (long)n * SPLIT;
    int blocks = (int)((total + BLK - 1) / BLK);
    ptd_kernel<<<blocks, BLK, 0, stream>>>(offset, points, tri_table, out, n);
}